// Round 14
// baseline (328.659 us; speedup 1.0000x reference)
//
#include <hip/hip_runtime.h>
#include <stdint.h>

#define SLEN 2048
#define EDIM 1024
#define NH 16
#define HD 64
#define QLD 1152   // qkv packed row: [q 0..1023 | k 1024..1087 | v 1088..1151]

typedef unsigned short u16;
typedef short bf8 __attribute__((ext_vector_type(8)));   // 8 bf16 in 4 VGPRs
typedef float f4 __attribute__((ext_vector_type(4)));
typedef bf8 bf8_a __attribute__((may_alias));
typedef uint2 uint2_a __attribute__((may_alias));
typedef uint4 uint4_a __attribute__((may_alias));
typedef float4 float4_a __attribute__((may_alias));

__device__ __forceinline__ float bf2f(u16 u) {
  union { unsigned u; float f; } c; c.u = ((unsigned)u) << 16; return c.f;
}
__device__ __forceinline__ u16 f2bf(float x) {
  union { __bf16 h; u16 u; } c; c.h = (__bf16)x; return c.u;  // HW cvt, RNE
}
__device__ __forceinline__ unsigned pk2bf(float a, float b) {
  union { __bf16 h[2]; unsigned u; } c;
  c.h[0] = (__bf16)a; c.h[1] = (__bf16)b;
  return c.u;
}
__device__ __forceinline__ void async_cp16(u16* lds, const u16* g) {
  __builtin_amdgcn_global_load_lds((__attribute__((address_space(1))) void*)g,
                                   (__attribute__((address_space(3))) void*)lds,
                                   16, 0, 0);
}

// ---------------- prep: weight transposes + bias -----------------------------
__device__ __forceinline__ void tcvt_tile(const float* src, int srcLd,
                                          u16* dst, int dstLd, int r0, int c0) {
  __shared__ u16 tile[64][65];
  const int t = threadIdx.x;
#pragma unroll
  for (int i = 0; i < 16; ++i) {
    int e = i * 256 + t, rr = e >> 6, cc = e & 63;
    tile[rr][cc] = f2bf(src[(size_t)(r0 + rr) * srcLd + c0 + cc]);
  }
  __syncthreads();
#pragma unroll
  for (int i = 0; i < 16; ++i) {
    int e = i * 256 + t, j = e >> 6, ii = e & 63;
    dst[(size_t)(c0 + j) * dstLd + r0 + ii] = tile[ii][j];
  }
}

__global__ void prep_w(const float* wq, const float* wk, const float* wv,
                       const float* wo, const float* bq, const float* bk,
                       const float* bv, const float* bo,
                       u16* wT, u16* woT, float* bQKV, float* bOut) {
  const int yy = blockIdx.y;
  if (yy < 16) tcvt_tile(wq, 1024, wT, 1024, blockIdx.x * 64, yy * 64);
  else if (yy < 32) tcvt_tile(wo, 1024, woT, 1024, blockIdx.x * 64, (yy - 16) * 64);
  else if (yy == 32) tcvt_tile(wk, 64, wT + (size_t)1024 * 1024, 1024, blockIdx.x * 64, 0);
  else if (yy == 33) tcvt_tile(wv, 64, wT + (size_t)1088 * 1024, 1024, blockIdx.x * 64, 0);
  else {
    int i = blockIdx.x * 256 + threadIdx.x;
    if (i < 1024) bQKV[i] = bq[i];
    else if (i < 1088) bQKV[i] = bk[i - 1024];
    else if (i < 1152) bQKV[i] = bv[i - 1088];
    int j = i - 1152;
    if (j >= 0 && j < 1024) bOut[j] = bo[j];
  }
}

// ---------------- QKV GEMM: A = x (fp32, converted in staging) ---------------
__global__ __launch_bounds__(256) void gemm_qkv(
    const float* __restrict__ X, const u16* __restrict__ Bt,
    const float* __restrict__ bias, u16* __restrict__ C,
    u16* __restrict__ vtb) {
  __shared__ __align__(16) u16 As[64 * 64];
  __shared__ __align__(16) u16 Bs[128 * 64];
  const int K = 1024;
  const int tn0 = blockIdx.x * 128, tm0 = blockIdx.y * 64;
  const int tid = threadIdx.x, wave = tid >> 6, lane = tid & 63;
  const int quad = lane >> 4, l16 = lane & 15;
  const int wm = wave & 1, wn = wave >> 1;

  f4 acc[2][4];
#pragma unroll
  for (int i = 0; i < 2; ++i)
#pragma unroll
    for (int j = 0; j < 4; ++j) acc[i][j] = f4{0.f, 0.f, 0.f, 0.f};

  int aslot[2], bslot[4]; size_t aoff[2], boff[4];
#pragma unroll
  for (int i = 0; i < 2; ++i) {
    int s = i * 256 + tid, m = s >> 3, kc = s & 7, c = (kc - m) & 7;
    aslot[i] = s; aoff[i] = (size_t)(tm0 + m) * K + c * 8;
  }
#pragma unroll
  for (int i = 0; i < 4; ++i) {
    int s = i * 256 + tid, n = s >> 3, kc = s & 7, c = (kc - n) & 7;
    bslot[i] = s; boff[i] = (size_t)(tn0 + n) * K + c * 8;
  }
  int ard[2][2], brd[4][2];
#pragma unroll
  for (int mi = 0; mi < 2; ++mi) {
    int m = wm * 32 + mi * 16 + l16;
#pragma unroll
    for (int kk = 0; kk < 2; ++kk)
      ard[mi][kk] = (m * 8 + (((kk * 4 + quad) + m) & 7)) * 8;
  }
#pragma unroll
  for (int ni = 0; ni < 4; ++ni) {
    int n = wn * 64 + ni * 16 + l16;
#pragma unroll
    for (int kk = 0; kk < 2; ++kk)
      brd[ni][kk] = (n * 8 + (((kk * 4 + quad) + n) & 7)) * 8;
  }

  for (int it = 0; it < 16; ++it) {
    const size_t kb = (size_t)it * 64;
    uint4 staged[2];
#pragma unroll
    for (int i = 0; i < 2; ++i) {
      float4 f0 = *(const float4_a*)(X + aoff[i] + kb);
      float4 f1 = *(const float4_a*)(X + aoff[i] + kb + 4);
      staged[i].x = pk2bf(f0.x, f0.y);
      staged[i].y = pk2bf(f0.z, f0.w);
      staged[i].z = pk2bf(f1.x, f1.y);
      staged[i].w = pk2bf(f1.z, f1.w);
    }
    __syncthreads();  // prior frag reads done
#pragma unroll
    for (int i = 0; i < 2; ++i) *(uint4_a*)&As[aslot[i] * 8] = staged[i];
#pragma unroll
    for (int i = 0; i < 4; ++i) async_cp16(&Bs[bslot[i] * 8], Bt + boff[i] + kb);
    __syncthreads();
#pragma unroll
    for (int kk = 0; kk < 2; ++kk) {
      bf8 af[2], bfr[4];
#pragma unroll
      for (int mi = 0; mi < 2; ++mi) af[mi] = *(const bf8_a*)&As[ard[mi][kk]];
#pragma unroll
      for (int ni = 0; ni < 4; ++ni) bfr[ni] = *(const bf8_a*)&Bs[brd[ni][kk]];
#pragma unroll
      for (int mi = 0; mi < 2; ++mi)
#pragma unroll
        for (int ni = 0; ni < 4; ++ni)
          acc[mi][ni] = __builtin_amdgcn_mfma_f32_16x16x32_bf16(
              af[mi], bfr[ni], acc[mi][ni], 0, 0, 0);
    }
  }

  float bv[4];
#pragma unroll
  for (int ni = 0; ni < 4; ++ni) bv[ni] = bias[tn0 + wn * 64 + ni * 16 + l16];
#pragma unroll
  for (int mi = 0; mi < 2; ++mi) {
    int row0 = tm0 + wm * 32 + mi * 16 + quad * 4;
#pragma unroll
    for (int ni = 0; ni < 4; ++ni) {
      int col = tn0 + wn * 64 + ni * 16 + l16;
      float vv[4];
#pragma unroll
      for (int r = 0; r < 4; ++r) vv[r] = acc[mi][ni][r] + bv[ni];
#pragma unroll
      for (int r = 0; r < 4; ++r)
        C[(size_t)(row0 + r) * QLD + col] = f2bf(vv[r]);
      if (col >= 1088) {
        int d = col - 1088, bb = row0 >> 11, s0 = row0 & 2047;
        uint2 pk;
        pk.x = pk2bf(vv[0], vv[1]);
        pk.y = pk2bf(vv[2], vv[3]);
        *(uint2_a*)&vtb[(size_t)(bb * 64 + d) * SLEN + s0] = pk;
      }
    }
  }
}

// ---------------- flash attention: nt=4 wave-key-split -----------------------
// Block: 4 waves = (qhalf, khalf). Each wave: 64 q-rows (nt=4) x half the
// 128-key tile -> K/V frag reads amortize over 4 MFMAs (24 b128/wave/kt for
// 64 MFMA vs R11's 40/64). khalf = extra split-K part (reduce_o combines 4).
// Grid (16,32,2); LDS 48KB; VGPR-bound 3 blocks/CU = 12 waves.
__global__ __launch_bounds__(256, 3) void attn_kernel(
    const u16* __restrict__ qkv, const u16* __restrict__ vT,
    u16* __restrict__ Opart, float* __restrict__ lpart) {
  __shared__ __align__(16) u16 Kf[8192];    // K tile frag-major; Qf in prologue
  __shared__ __align__(16) u16 Vf[8192];
  __shared__ __align__(16) u16 Ps[8192];    // 4 waves x 2048
  const int qt = blockIdx.x, bh = blockIdx.y, ks = blockIdx.z;
  const int b = bh >> 4, h = bh & 15;
  const int tid = threadIdx.x, wave = tid >> 6, lane = tid & 63;
  const int quad = lane >> 4, l16 = lane & 15;
  const int qhalf = wave & 1, khalf = wave >> 1;

  // Qf stage: chunk d = [kk:1][g:3][qd:2][r16:4] (128 q-rows)
#pragma unroll
  for (int i = 0; i < 4; ++i) {
    int d = i * 256 + tid;
    int kk = d >> 9, g = (d >> 6) & 7, qd = (d >> 4) & 3, r16 = d & 15;
    async_cp16(&Kf[d * 8],
               qkv + (size_t)(b * SLEN + qt * 128 + g * 16 + r16) * QLD +
                   h * HD + (kk * 4 + qd) * 8);
  }
  __syncthreads();
  bf8 bq[4][2];  // [nt][kk]: B-frag rows qhalf*64 + nt*16 + l16
#pragma unroll
  for (int nt = 0; nt < 4; ++nt)
#pragma unroll
    for (int kk = 0; kk < 2; ++kk)
      bq[nt][kk] = *(const bf8_a*)&Kf[((kk * 8 + qhalf * 4 + nt) * 64 + lane) * 8];

  f4 acc_o[4][4];
#pragma unroll
  for (int i = 0; i < 4; ++i)
#pragma unroll
    for (int j = 0; j < 4; ++j) acc_o[i][j] = f4{0.f, 0.f, 0.f, 0.f};
  float lr[4] = {0.f, 0.f, 0.f, 0.f};
  const float C1 = 0.125f * 1.44269504089f;  // scale * log2(e)
  const int psb = wave * 2048;

  for (int kt = ks * 8; kt < ks * 8 + 8; ++kt) {
    __syncthreads();  // prior Kf/Vf reads (incl. bq prologue) complete
    // Kf: chunk d = [kk:1][k8:3][qd:2][r16:4] (128 keys)
#pragma unroll
    for (int i = 0; i < 4; ++i) {
      int d = i * 256 + tid;
      int kk = d >> 9, k8 = (d >> 6) & 7, qd = (d >> 4) & 3, r16 = d & 15;
      async_cp16(&Kf[d * 8],
                 qkv + (size_t)(b * SLEN + kt * 128 + k8 * 16 + r16) * QLD +
                     EDIM + (kk * 4 + qd) * 8);
    }
    // Vf: chunk d = [k4:2][ni:2][qd:2][r16:4]
#pragma unroll
    for (int i = 0; i < 4; ++i) {
      int d = i * 256 + tid;
      int k4 = d >> 8, ni = (d >> 6) & 3, qd = (d >> 4) & 3, r16 = d & 15;
      async_cp16(&Vf[d * 8],
                 vT + (size_t)(b * 64 + ni * 16 + r16) * SLEN + kt * 128 +
                     (k4 * 4 + qd) * 8);
    }
    __syncthreads();

    // wave's two 32-key groups: QK -> softmax/pack -> wave-private Ps -> PV
#pragma unroll
    for (int g4 = 0; g4 < 2; ++g4) {
      const int k4 = khalf * 2 + g4;
      f4 st[2][4];  // [j][nt]
#pragma unroll
      for (int j = 0; j < 2; ++j)
#pragma unroll
        for (int nt = 0; nt < 4; ++nt) st[j][nt] = f4{0.f, 0.f, 0.f, 0.f};
#pragma unroll
      for (int kk = 0; kk < 2; ++kk)
#pragma unroll
        for (int j = 0; j < 2; ++j) {
          bf8 ak = *(const bf8_a*)&Kf[((kk * 8 + k4 * 2 + j) * 64 + lane) * 8];
#pragma unroll
          for (int nt = 0; nt < 4; ++nt)
            st[j][nt] = __builtin_amdgcn_mfma_f32_16x16x32_bf16(
                ak, bq[nt][kk], st[j][nt], 0, 0, 0);
        }
#pragma unroll
      for (int nt = 0; nt < 4; ++nt)
#pragma unroll
        for (int j = 0; j < 2; ++j) {
          float p0 = __builtin_amdgcn_exp2f(st[j][nt][0] * C1);
          float p1 = __builtin_amdgcn_exp2f(st[j][nt][1] * C1);
          float p2 = __builtin_amdgcn_exp2f(st[j][nt][2] * C1);
          float p3 = __builtin_amdgcn_exp2f(st[j][nt][3] * C1);
          lr[nt] += (p0 + p1) + (p2 + p3);
          uint2 pk;
          pk.x = pk2bf(p0, p1);
          pk.y = pk2bf(p2, p3);
          int qd2 = j * 2 + (quad >> 1);
          *(uint2_a*)&Ps[psb + ((nt * 4 + qd2) * 16 + l16) * 8 + (quad & 1) * 4] = pk;
        }
      asm volatile("" ::: "memory");  // Ps writes before PV reads (same wave)
      bf8 ap[4];
#pragma unroll
      for (int mt = 0; mt < 4; ++mt)
        ap[mt] = *(const bf8_a*)&Ps[psb + ((mt * 4 + quad) * 16 + l16) * 8];
#pragma unroll
      for (int ni = 0; ni < 4; ++ni) {
        bf8 bv = *(const bf8_a*)&Vf[((k4 * 4 + ni) * 64 + lane) * 8];
#pragma unroll
        for (int mt = 0; mt < 4; ++mt)
          acc_o[mt][ni] = __builtin_amdgcn_mfma_f32_16x16x32_bf16(
              ap[mt], bv, acc_o[mt][ni], 0, 0, 0);
      }
      asm volatile("" ::: "memory");  // PV reads before next group's Ps writes
    }
  }

  // store unnormalized partials: part p = ks*2 + khalf; rows qhalf*64..+64
  const int p = ks * 2 + khalf;
  const size_t pbase = (size_t)((p * 32 + bh) * 16 + qt) * 128 + qhalf * 64;
#pragma unroll
  for (int nt = 0; nt < 4; ++nt) {
    float s = lr[nt];
    s += __shfl_xor(s, 16, 64);
    s += __shfl_xor(s, 32, 64);
    if (quad == 0) lpart[pbase + nt * 16 + l16] = s;
  }
#pragma unroll
  for (int mt = 0; mt < 4; ++mt)
#pragma unroll
    for (int r = 0; r < 4; ++r) {
      size_t row = pbase + mt * 16 + quad * 4 + r;
#pragma unroll
      for (int ni = 0; ni < 4; ++ni)
        Opart[row * 64 + ni * 16 + l16] = f2bf(acc_o[mt][ni][r]);
    }
}

// ---------------- combine 4 split-K parts: aob = (ΣO_p)/(Σl_p) ---------------
__global__ __launch_bounds__(256) void reduce_o(const u16* __restrict__ Op,
                                                const float* __restrict__ lp,
                                                u16* __restrict__ aob) {
  const int qt = blockIdx.x, bh = blockIdx.y, b = bh >> 4, h = bh & 15;
  const int t = threadIdx.x, r = t >> 1, dh = (t & 1) * 32;
  const size_t p0 = (size_t)(bh * 16 + qt) * 128 + r;  // part stride 65536 rows
  float lsum = 0.f;
#pragma unroll
  for (int p = 0; p < 4; ++p) lsum += lp[p0 + (size_t)p * 65536];
  const float inv = 1.f / lsum;
  u16* dst = aob + (size_t)(b * SLEN + qt * 128 + r) * EDIM + h * HD + dh;
#pragma unroll
  for (int c = 0; c < 4; ++c) {
    uint4 ap[4];
#pragma unroll
    for (int p = 0; p < 4; ++p)
      ap[p] = *(const uint4_a*)(Op + (p0 + (size_t)p * 65536) * 64 + dh + c * 8);
    u16 outv[8];
#pragma unroll
    for (int j = 0; j < 8; ++j) {
      float s = bf2f(((const u16*)&ap[0])[j]) + bf2f(((const u16*)&ap[1])[j]) +
                bf2f(((const u16*)&ap[2])[j]) + bf2f(((const u16*)&ap[3])[j]);
      outv[j] = f2bf(s * inv);
    }
    *(uint4_a*)(dst + c * 8) = *(const uint4_a*)outv;
  }
}

// ---------------- out GEMM: plain bf16 A (aob), fp32 epilogue ----------------
__global__ __launch_bounds__(256) void gemm_out(
    const u16* __restrict__ A, const u16* __restrict__ Bt,
    const float* __restrict__ bias, float* __restrict__ C) {
  __shared__ __align__(16) u16 As[64 * 64];
  __shared__ __align__(16) u16 Bs[128 * 64];
  const int K = 1024;
  const int tn0 = blockIdx.x * 128, tm0 = blockIdx.y * 64;
  const int tid = threadIdx.x, wave = tid >> 6, lane = tid & 63;
  const int quad = lane >> 4, l16 = lane & 15;
  const int wm = wave & 1, wn = wave >> 1;

  f4 acc[2][4];
#pragma unroll
  for (int i = 0; i < 2; ++i)
#pragma unroll
    for (int j = 0; j < 4; ++j) acc[i][j] = f4{0.f, 0.f, 0.f, 0.f};

  int aslot[2], bslot[4]; size_t aoff[2], boff[4];
#pragma unroll
  for (int i = 0; i < 2; ++i) {
    int s = i * 256 + tid, m = s >> 3, kc = s & 7, c = (kc - m) & 7;
    aslot[i] = s; aoff[i] = (size_t)(tm0 + m) * K + c * 8;
  }
#pragma unroll
  for (int i = 0; i < 4; ++i) {
    int s = i * 256 + tid, n = s >> 3, kc = s & 7, c = (kc - n) & 7;
    bslot[i] = s; boff[i] = (size_t)(tn0 + n) * K + c * 8;
  }
  int ard[2][2], brd[4][2];
#pragma unroll
  for (int mi = 0; mi < 2; ++mi) {
    int m = wm * 32 + mi * 16 + l16;
#pragma unroll
    for (int kk = 0; kk < 2; ++kk)
      ard[mi][kk] = (m * 8 + (((kk * 4 + quad) + m) & 7)) * 8;
  }
#pragma unroll
  for (int ni = 0; ni < 4; ++ni) {
    int n = wn * 64 + ni * 16 + l16;
#pragma unroll
    for (int kk = 0; kk < 2; ++kk)
      brd[ni][kk] = (n * 8 + (((kk * 4 + quad) + n) & 7)) * 8;
  }

  for (int it = 0; it < 16; ++it) {
    __syncthreads();
    const size_t kb = (size_t)it * 64;
#pragma unroll
    for (int i = 0; i < 2; ++i) async_cp16(&As[aslot[i] * 8], A + aoff[i] + kb);
#pragma unroll
    for (int i = 0; i < 4; ++i) async_cp16(&Bs[bslot[i] * 8], Bt + boff[i] + kb);
    __syncthreads();
#pragma unroll
    for (int kk = 0; kk < 2; ++kk) {
      bf8 af[2], bfr[4];
#pragma unroll
      for (int mi = 0; mi < 2; ++mi) af[mi] = *(const bf8_a*)&As[ard[mi][kk]];
#pragma unroll
      for (int ni = 0; ni < 4; ++ni) bfr[ni] = *(const bf8_a*)&Bs[brd[ni][kk]];
#pragma unroll
      for (int mi = 0; mi < 2; ++mi)
#pragma unroll
        for (int ni = 0; ni < 4; ++ni)
          acc[mi][ni] = __builtin_amdgcn_mfma_f32_16x16x32_bf16(
              af[mi], bfr[ni], acc[mi][ni], 0, 0, 0);
    }
  }

  float bv[4];
#pragma unroll
  for (int ni = 0; ni < 4; ++ni) bv[ni] = bias[tn0 + wn * 64 + ni * 16 + l16];
#pragma unroll
  for (int mi = 0; mi < 2; ++mi) {
    int row0 = tm0 + wm * 32 + mi * 16 + quad * 4;
#pragma unroll
    for (int ni = 0; ni < 4; ++ni) {
      int col = tn0 + wn * 64 + ni * 16 + l16;
#pragma unroll
      for (int r = 0; r < 4; ++r)
        C[(size_t)(row0 + r) * 1024 + col] = acc[mi][ni][r] + bv[ni];
    }
  }
}

// ---------------- host ------------------------------------------------------
extern "C" void kernel_launch(void* const* d_in, const int* in_sizes, int n_in,
                              void* d_out, int out_size, void* d_ws, size_t ws_size,
                              hipStream_t stream) {
  const float* x  = (const float*)d_in[0];
  const float* wq = (const float*)d_in[1];
  const float* bq = (const float*)d_in[2];
  const float* wk = (const float*)d_in[3];
  const float* bk = (const float*)d_in[4];
  const float* wv = (const float*)d_in[5];
  const float* bv = (const float*)d_in[6];
  const float* wo = (const float*)d_in[7];
  const float* bo = (const float*)d_in[8];

  char* ws = (char*)d_ws;
  size_t off = 0;
  auto carve = [&](size_t bytes) {
    void* p = ws + off;
    off = (off + bytes + 255) & ~(size_t)255;
    return p;
  };
  u16* wT      = (u16*)carve((size_t)1152 * 1024 * 2);  // packed [wq|wk|wv]^T
  u16* woT     = (u16*)carve((size_t)1024 * 1024 * 2);
  float* bQKV  = (float*)carve(1152 * 4);
  float* bOut  = (float*)carve(1024 * 4);
  u16* qkvb    = (u16*)carve((size_t)4096 * QLD * 2);
  u16* vTb     = (u16*)carve((size_t)2 * 64 * SLEN * 2);
  u16* Opart   = (u16*)carve((size_t)4 * 32 * 16 * 128 * 64 * 2);  // 33.6 MB
  float* lpart = (float*)carve((size_t)4 * 32 * 16 * 128 * 4);     // 1 MB
  u16* aob     = qkvb;  // qkvb dead after attn_kernel; reuse (8.4 <= 9.4 MB)

  // prep: weight transposes + bias
  prep_w<<<dim3(16, 35), 256, 0, stream>>>(wq, wk, wv, wo, bq, bk, bv, bo,
                                           wT, woT, bQKV, bOut);

  // QKV projection (x converted in staging) + fused V-transpose
  gemm_qkv<<<dim3(9, 64), 256, 0, stream>>>(x, wT, bQKV, qkvb, vTb);

  // flash attention: split-K x2 grid dim + khalf wave split = 4 parts
  attn_kernel<<<dim3(16, 32, 2), 256, 0, stream>>>(qkvb, vTb, Opart, lpart);

  // combine parts (single pass over Opart)
  reduce_o<<<dim3(16, 32), 256, 0, stream>>>(Opart, lpart, aob);

  // output projection -> d_out fp32
  gemm_out<<<dim3(8, 64), 256, 0, stream>>>(aob, woT, bOut, (float*)d_out);
}

// Round 15
// 192.048 us; speedup vs baseline: 1.7113x; 1.7113x over previous
//
#include <hip/hip_runtime.h>
#include <stdint.h>

#define SLEN 2048
#define EDIM 1024
#define NH 16
#define HD 64
#define QLD 1152   // qkv packed row: [q 0..1023 | k 1024..1087 | v 1088..1151]

typedef unsigned short u16;
typedef short bf8 __attribute__((ext_vector_type(8)));   // 8 bf16 in 4 VGPRs
typedef float f4 __attribute__((ext_vector_type(4)));
typedef bf8 bf8_a __attribute__((may_alias));
typedef uint2 uint2_a __attribute__((may_alias));
typedef uint4 uint4_a __attribute__((may_alias));
typedef float4 float4_a __attribute__((may_alias));

__device__ __forceinline__ float bf2f(u16 u) {
  union { unsigned u; float f; } c; c.u = ((unsigned)u) << 16; return c.f;
}
__device__ __forceinline__ u16 f2bf(float x) {
  union { __bf16 h; u16 u; } c; c.h = (__bf16)x; return c.u;  // HW cvt, RNE
}
__device__ __forceinline__ unsigned pk2bf(float a, float b) {
  union { __bf16 h[2]; unsigned u; } c;
  c.h[0] = (__bf16)a; c.h[1] = (__bf16)b;
  return c.u;
}
__device__ __forceinline__ void async_cp16(u16* lds, const u16* g) {
  __builtin_amdgcn_global_load_lds((__attribute__((address_space(1))) void*)g,
                                   (__attribute__((address_space(3))) void*)lds,
                                   16, 0, 0);
}

// ---------------- prep: weight transposes + bias -----------------------------
__device__ __forceinline__ void tcvt_tile(const float* src, int srcLd,
                                          u16* dst, int dstLd, int r0, int c0) {
  __shared__ u16 tile[64][65];
  const int t = threadIdx.x;
#pragma unroll
  for (int i = 0; i < 16; ++i) {
    int e = i * 256 + t, rr = e >> 6, cc = e & 63;
    tile[rr][cc] = f2bf(src[(size_t)(r0 + rr) * srcLd + c0 + cc]);
  }
  __syncthreads();
#pragma unroll
  for (int i = 0; i < 16; ++i) {
    int e = i * 256 + t, j = e >> 6, ii = e & 63;
    dst[(size_t)(c0 + j) * dstLd + r0 + ii] = tile[ii][j];
  }
}

__global__ void prep_w(const float* wq, const float* wk, const float* wv,
                       const float* wo, const float* bq, const float* bk,
                       const float* bv, const float* bo,
                       u16* wT, u16* woT, float* bQKV, float* bOut) {
  const int yy = blockIdx.y;
  if (yy < 16) tcvt_tile(wq, 1024, wT, 1024, blockIdx.x * 64, yy * 64);
  else if (yy < 32) tcvt_tile(wo, 1024, woT, 1024, blockIdx.x * 64, (yy - 16) * 64);
  else if (yy == 32) tcvt_tile(wk, 64, wT + (size_t)1024 * 1024, 1024, blockIdx.x * 64, 0);
  else if (yy == 33) tcvt_tile(wv, 64, wT + (size_t)1088 * 1024, 1024, blockIdx.x * 64, 0);
  else {
    int i = blockIdx.x * 256 + threadIdx.x;
    if (i < 1024) bQKV[i] = bq[i];
    else if (i < 1088) bQKV[i] = bk[i - 1024];
    else if (i < 1152) bQKV[i] = bv[i - 1088];
    int j = i - 1152;
    if (j >= 0 && j < 1024) bOut[j] = bo[j];
  }
}

// ---------------- QKV GEMM: A = x (fp32, converted in staging) ---------------
// Verified neutral vs separate convert (R12-R14 non-attn constant ~126us).
__global__ __launch_bounds__(256) void gemm_qkv(
    const float* __restrict__ X, const u16* __restrict__ Bt,
    const float* __restrict__ bias, u16* __restrict__ C,
    u16* __restrict__ vtb) {
  __shared__ __align__(16) u16 As[64 * 64];
  __shared__ __align__(16) u16 Bs[128 * 64];
  const int K = 1024;
  const int tn0 = blockIdx.x * 128, tm0 = blockIdx.y * 64;
  const int tid = threadIdx.x, wave = tid >> 6, lane = tid & 63;
  const int quad = lane >> 4, l16 = lane & 15;
  const int wm = wave & 1, wn = wave >> 1;

  f4 acc[2][4];
#pragma unroll
  for (int i = 0; i < 2; ++i)
#pragma unroll
    for (int j = 0; j < 4; ++j) acc[i][j] = f4{0.f, 0.f, 0.f, 0.f};

  int aslot[2], bslot[4]; size_t aoff[2], boff[4];
#pragma unroll
  for (int i = 0; i < 2; ++i) {
    int s = i * 256 + tid, m = s >> 3, kc = s & 7, c = (kc - m) & 7;
    aslot[i] = s; aoff[i] = (size_t)(tm0 + m) * K + c * 8;
  }
#pragma unroll
  for (int i = 0; i < 4; ++i) {
    int s = i * 256 + tid, n = s >> 3, kc = s & 7, c = (kc - n) & 7;
    bslot[i] = s; boff[i] = (size_t)(tn0 + n) * K + c * 8;
  }
  int ard[2][2], brd[4][2];
#pragma unroll
  for (int mi = 0; mi < 2; ++mi) {
    int m = wm * 32 + mi * 16 + l16;
#pragma unroll
    for (int kk = 0; kk < 2; ++kk)
      ard[mi][kk] = (m * 8 + (((kk * 4 + quad) + m) & 7)) * 8;
  }
#pragma unroll
  for (int ni = 0; ni < 4; ++ni) {
    int n = wn * 64 + ni * 16 + l16;
#pragma unroll
    for (int kk = 0; kk < 2; ++kk)
      brd[ni][kk] = (n * 8 + (((kk * 4 + quad) + n) & 7)) * 8;
  }

  for (int it = 0; it < 16; ++it) {
    const size_t kb = (size_t)it * 64;
    uint4 staged[2];
#pragma unroll
    for (int i = 0; i < 2; ++i) {
      float4 f0 = *(const float4_a*)(X + aoff[i] + kb);
      float4 f1 = *(const float4_a*)(X + aoff[i] + kb + 4);
      staged[i].x = pk2bf(f0.x, f0.y);
      staged[i].y = pk2bf(f0.z, f0.w);
      staged[i].z = pk2bf(f1.x, f1.y);
      staged[i].w = pk2bf(f1.z, f1.w);
    }
    __syncthreads();  // prior frag reads done
#pragma unroll
    for (int i = 0; i < 2; ++i) *(uint4_a*)&As[aslot[i] * 8] = staged[i];
#pragma unroll
    for (int i = 0; i < 4; ++i) async_cp16(&Bs[bslot[i] * 8], Bt + boff[i] + kb);
    __syncthreads();
#pragma unroll
    for (int kk = 0; kk < 2; ++kk) {
      bf8 af[2], bfr[4];
#pragma unroll
      for (int mi = 0; mi < 2; ++mi) af[mi] = *(const bf8_a*)&As[ard[mi][kk]];
#pragma unroll
      for (int ni = 0; ni < 4; ++ni) bfr[ni] = *(const bf8_a*)&Bs[brd[ni][kk]];
#pragma unroll
      for (int mi = 0; mi < 2; ++mi)
#pragma unroll
        for (int ni = 0; ni < 4; ++ni)
          acc[mi][ni] = __builtin_amdgcn_mfma_f32_16x16x32_bf16(
              af[mi], bfr[ni], acc[mi][ni], 0, 0, 0);
    }
  }

  float bv[4];
#pragma unroll
  for (int ni = 0; ni < 4; ++ni) bv[ni] = bias[tn0 + wn * 64 + ni * 16 + l16];
#pragma unroll
  for (int mi = 0; mi < 2; ++mi) {
    int row0 = tm0 + wm * 32 + mi * 16 + quad * 4;
#pragma unroll
    for (int ni = 0; ni < 4; ++ni) {
      int col = tn0 + wn * 64 + ni * 16 + l16;
      float vv[4];
#pragma unroll
      for (int r = 0; r < 4; ++r) vv[r] = acc[mi][ni][r] + bv[ni];
#pragma unroll
      for (int r = 0; r < 4; ++r)
        C[(size_t)(row0 + r) * QLD + col] = f2bf(vv[r]);
      if (col >= 1088) {
        int d = col - 1088, bb = row0 >> 11, s0 = row0 & 2047;
        uint2 pk;
        pk.x = pk2bf(vv[0], vv[1]);
        pk.y = pk2bf(vv[2], vv[3]);
        *(uint2_a*)&vtb[(size_t)(bb * 64 + d) * SLEN + s0] = pk;
      }
    }
  }
}

// ---------------- flash attention (R11-bench proven: 58.5us, VGPR 60) --------
// 256 thr = 4 waves x 32 q-rows; 128-key k-tiles; LDS 40KB (4 blocks/CU);
// grid (16,32,2) split-K. No-max softmax partials: O bf16 + l fp32.
__global__ __launch_bounds__(256, 4) void attn_kernel(
    const u16* __restrict__ qkv, const u16* __restrict__ vT,
    u16* __restrict__ Opart, float* __restrict__ lpart) {
  __shared__ __align__(16) u16 Kf[8192];    // K tile frag-major; Qf in prologue
  __shared__ __align__(16) u16 Vf[8192];
  __shared__ __align__(16) u16 Ps[4096];    // 4 waves x 1024 (one 32-key group)
  const int qt = blockIdx.x, bh = blockIdx.y, ks = blockIdx.z;
  const int b = bh >> 4, h = bh & 15;
  const int tid = threadIdx.x, wave = tid >> 6, lane = tid & 63;
  const int quad = lane >> 4, l16 = lane & 15;

  // Qf stage: chunk d = [kk:1][g:3][qd:2][r16:4]
#pragma unroll
  for (int i = 0; i < 4; ++i) {
    int d = i * 256 + tid;
    int kk = d >> 9, g = (d >> 6) & 7, qd = (d >> 4) & 3, r16 = d & 15;
    async_cp16(&Kf[d * 8],
               qkv + (size_t)(b * SLEN + qt * 128 + g * 16 + r16) * QLD +
                   h * HD + (kk * 4 + qd) * 8);
  }
  __syncthreads();
  bf8 bq[2][2];  // [nt][kk], B-frag rows wave*32 + nt*16 + l16
#pragma unroll
  for (int nt = 0; nt < 2; ++nt)
#pragma unroll
    for (int kk = 0; kk < 2; ++kk)
      bq[nt][kk] = *(const bf8_a*)&Kf[((kk * 8 + wave * 2 + nt) * 64 + lane) * 8];

  f4 acc_o[2][4];
#pragma unroll
  for (int i = 0; i < 2; ++i)
#pragma unroll
    for (int j = 0; j < 4; ++j) acc_o[i][j] = f4{0.f, 0.f, 0.f, 0.f};
  f4 lr4[2] = {f4{0.f, 0.f, 0.f, 0.f}, f4{0.f, 0.f, 0.f, 0.f}};
  const float C1 = 0.125f * 1.44269504089f;  // scale * log2(e)
  const int psb = wave * 1024;

  for (int kt = ks * 8; kt < ks * 8 + 8; ++kt) {
    __syncthreads();  // prior Kf/Vf reads (incl. bq prologue) complete
#pragma unroll
    for (int i = 0; i < 4; ++i) {
      int d = i * 256 + tid;
      int kk = d >> 9, k8 = (d >> 6) & 7, qd = (d >> 4) & 3, r16 = d & 15;
      async_cp16(&Kf[d * 8],
                 qkv + (size_t)(b * SLEN + kt * 128 + k8 * 16 + r16) * QLD +
                     EDIM + (kk * 4 + qd) * 8);
    }
#pragma unroll
    for (int i = 0; i < 4; ++i) {
      int d = i * 256 + tid;
      int k4 = d >> 8, ni = (d >> 6) & 3, qd = (d >> 4) & 3, r16 = d & 15;
      async_cp16(&Vf[d * 8],
                 vT + (size_t)(b * 64 + ni * 16 + r16) * SLEN + kt * 128 +
                     (k4 * 4 + qd) * 8);
    }
    __syncthreads();

    // per-32-key fused groups: QK -> softmax/pack -> wave-private Ps -> PV
#pragma unroll
    for (int k4 = 0; k4 < 4; ++k4) {
      f4 st[2][2];
#pragma unroll
      for (int j = 0; j < 2; ++j)
#pragma unroll
        for (int nt = 0; nt < 2; ++nt) st[j][nt] = f4{0.f, 0.f, 0.f, 0.f};
#pragma unroll
      for (int kk = 0; kk < 2; ++kk)
#pragma unroll
        for (int j = 0; j < 2; ++j) {
          bf8 ak = *(const bf8_a*)&Kf[((kk * 8 + k4 * 2 + j) * 64 + lane) * 8];
#pragma unroll
          for (int nt = 0; nt < 2; ++nt)
            st[j][nt] = __builtin_amdgcn_mfma_f32_16x16x32_bf16(
                ak, bq[nt][kk], st[j][nt], 0, 0, 0);
        }
#pragma unroll
      for (int nt = 0; nt < 2; ++nt)
#pragma unroll
        for (int j = 0; j < 2; ++j) {
          f4 pe;
          pe[0] = __builtin_amdgcn_exp2f(st[j][nt][0] * C1);
          pe[1] = __builtin_amdgcn_exp2f(st[j][nt][1] * C1);
          pe[2] = __builtin_amdgcn_exp2f(st[j][nt][2] * C1);
          pe[3] = __builtin_amdgcn_exp2f(st[j][nt][3] * C1);
          lr4[nt] += pe;
          uint2 pk;
          pk.x = pk2bf(pe[0], pe[1]);
          pk.y = pk2bf(pe[2], pe[3]);
          int qd2 = j * 2 + (quad >> 1);
          *(uint2_a*)&Ps[psb + ((nt * 4 + qd2) * 16 + l16) * 8 + (quad & 1) * 4] = pk;
        }
      asm volatile("" ::: "memory");  // Ps writes before PV reads (same wave)
      bf8 ap[2];
#pragma unroll
      for (int mt = 0; mt < 2; ++mt)
        ap[mt] = *(const bf8_a*)&Ps[psb + ((mt * 4 + quad) * 16 + l16) * 8];
#pragma unroll
      for (int ni = 0; ni < 4; ++ni) {
        bf8 bv = *(const bf8_a*)&Vf[((k4 * 4 + ni) * 64 + lane) * 8];
#pragma unroll
        for (int mt = 0; mt < 2; ++mt)
          acc_o[mt][ni] = __builtin_amdgcn_mfma_f32_16x16x32_bf16(
              ap[mt], bv, acc_o[mt][ni], 0, 0, 0);
      }
      asm volatile("" ::: "memory");  // PV reads before next group's Ps writes
    }
  }

  // store unnormalized partials: O bf16, l fp32
  const size_t pbase = (size_t)((ks * 32 + bh) * 16 + qt) * 128;
  float ls[2];
#pragma unroll
  for (int nt = 0; nt < 2; ++nt) {
    float s = (lr4[nt][0] + lr4[nt][1]) + (lr4[nt][2] + lr4[nt][3]);
    s += __shfl_xor(s, 16, 64);
    s += __shfl_xor(s, 32, 64);
    ls[nt] = s;
    if (quad == 0) lpart[pbase + wave * 32 + nt * 16 + l16] = s;
  }
#pragma unroll
  for (int mt = 0; mt < 2; ++mt)
#pragma unroll
    for (int r = 0; r < 4; ++r) {
      size_t row = pbase + wave * 32 + mt * 16 + quad * 4 + r;
#pragma unroll
      for (int ni = 0; ni < 4; ++ni)
        Opart[row * 64 + ni * 16 + l16] = f2bf(acc_o[mt][ni][r]);
    }
}

// ---------------- combine split-K halves: aob = (O0+O1)/(l0+l1) --------------
__global__ __launch_bounds__(256) void reduce_o(const u16* __restrict__ Op,
                                                const float* __restrict__ lp,
                                                u16* __restrict__ aob) {
  const int qt = blockIdx.x, bh = blockIdx.y, b = bh >> 4, h = bh & 15;
  const int t = threadIdx.x, r = t >> 1, dh = (t & 1) * 32;
  const size_t p0 = (size_t)(bh * 16 + qt) * 128;
  const size_t p1 = (size_t)((32 + bh) * 16 + qt) * 128;
  const float inv = 1.f / (lp[p0 + r] + lp[p1 + r]);
  const u16* o0 = Op + (p0 + r) * 64 + dh;
  const u16* o1 = Op + (p1 + r) * 64 + dh;
  u16* dst = aob + (size_t)(b * SLEN + qt * 128 + r) * EDIM + h * HD + dh;
#pragma unroll
  for (int c = 0; c < 4; ++c) {
    uint4 a = *(const uint4_a*)(o0 + c * 8);
    uint4 bb = *(const uint4_a*)(o1 + c * 8);
    const u16* pa = (const u16*)&a;
    const u16* pb = (const u16*)&bb;
    u16 outv[8];
#pragma unroll
    for (int j = 0; j < 8; ++j)
      outv[j] = f2bf((bf2f(pa[j]) + bf2f(pb[j])) * inv);
    *(uint4_a*)(dst + c * 8) = *(const uint4_a*)outv;
  }
}

// ---------------- out GEMM: plain bf16 A (aob), fp32 epilogue ----------------
__global__ __launch_bounds__(256) void gemm_out(
    const u16* __restrict__ A, const u16* __restrict__ Bt,
    const float* __restrict__ bias, float* __restrict__ C) {
  __shared__ __align__(16) u16 As[64 * 64];
  __shared__ __align__(16) u16 Bs[128 * 64];
  const int K = 1024;
  const int tn0 = blockIdx.x * 128, tm0 = blockIdx.y * 64;
  const int tid = threadIdx.x, wave = tid >> 6, lane = tid & 63;
  const int quad = lane >> 4, l16 = lane & 15;
  const int wm = wave & 1, wn = wave >> 1;

  f4 acc[2][4];
#pragma unroll
  for (int i = 0; i < 2; ++i)
#pragma unroll
    for (int j = 0; j < 4; ++j) acc[i][j] = f4{0.f, 0.f, 0.f, 0.f};

  int aslot[2], bslot[4]; size_t aoff[2], boff[4];
#pragma unroll
  for (int i = 0; i < 2; ++i) {
    int s = i * 256 + tid, m = s >> 3, kc = s & 7, c = (kc - m) & 7;
    aslot[i] = s; aoff[i] = (size_t)(tm0 + m) * K + c * 8;
  }
#pragma unroll
  for (int i = 0; i < 4; ++i) {
    int s = i * 256 + tid, n = s >> 3, kc = s & 7, c = (kc - n) & 7;
    bslot[i] = s; boff[i] = (size_t)(tn0 + n) * K + c * 8;
  }
  int ard[2][2], brd[4][2];
#pragma unroll
  for (int mi = 0; mi < 2; ++mi) {
    int m = wm * 32 + mi * 16 + l16;
#pragma unroll
    for (int kk = 0; kk < 2; ++kk)
      ard[mi][kk] = (m * 8 + (((kk * 4 + quad) + m) & 7)) * 8;
  }
#pragma unroll
  for (int ni = 0; ni < 4; ++ni) {
    int n = wn * 64 + ni * 16 + l16;
#pragma unroll
    for (int kk = 0; kk < 2; ++kk)
      brd[ni][kk] = (n * 8 + (((kk * 4 + quad) + n) & 7)) * 8;
  }

  for (int it = 0; it < 16; ++it) {
    __syncthreads();
    const size_t kb = (size_t)it * 64;
#pragma unroll
    for (int i = 0; i < 2; ++i) async_cp16(&As[aslot[i] * 8], A + aoff[i] + kb);
#pragma unroll
    for (int i = 0; i < 4; ++i) async_cp16(&Bs[bslot[i] * 8], Bt + boff[i] + kb);
    __syncthreads();
#pragma unroll
    for (int kk = 0; kk < 2; ++kk) {
      bf8 af[2], bfr[4];
#pragma unroll
      for (int mi = 0; mi < 2; ++mi) af[mi] = *(const bf8_a*)&As[ard[mi][kk]];
#pragma unroll
      for (int ni = 0; ni < 4; ++ni) bfr[ni] = *(const bf8_a*)&Bs[brd[ni][kk]];
#pragma unroll
      for (int mi = 0; mi < 2; ++mi)
#pragma unroll
        for (int ni = 0; ni < 4; ++ni)
          acc[mi][ni] = __builtin_amdgcn_mfma_f32_16x16x32_bf16(
              af[mi], bfr[ni], acc[mi][ni], 0, 0, 0);
    }
  }

  float bv[4];
#pragma unroll
  for (int ni = 0; ni < 4; ++ni) bv[ni] = bias[tn0 + wn * 64 + ni * 16 + l16];
#pragma unroll
  for (int mi = 0; mi < 2; ++mi) {
    int row0 = tm0 + wm * 32 + mi * 16 + quad * 4;
#pragma unroll
    for (int ni = 0; ni < 4; ++ni) {
      int col = tn0 + wn * 64 + ni * 16 + l16;
#pragma unroll
      for (int r = 0; r < 4; ++r)
        C[(size_t)(row0 + r) * 1024 + col] = acc[mi][ni][r] + bv[ni];
    }
  }
}

// ---------------- host ------------------------------------------------------
extern "C" void kernel_launch(void* const* d_in, const int* in_sizes, int n_in,
                              void* d_out, int out_size, void* d_ws, size_t ws_size,
                              hipStream_t stream) {
  const float* x  = (const float*)d_in[0];
  const float* wq = (const float*)d_in[1];
  const float* bq = (const float*)d_in[2];
  const float* wk = (const float*)d_in[3];
  const float* bk = (const float*)d_in[4];
  const float* wv = (const float*)d_in[5];
  const float* bv = (const float*)d_in[6];
  const float* wo = (const float*)d_in[7];
  const float* bo = (const float*)d_in[8];

  char* ws = (char*)d_ws;
  size_t off = 0;
  auto carve = [&](size_t bytes) {
    void* p = ws + off;
    off = (off + bytes + 255) & ~(size_t)255;
    return p;
  };
  u16* wT      = (u16*)carve((size_t)1152 * 1024 * 2);  // packed [wq|wk|wv]^T
  u16* woT     = (u16*)carve((size_t)1024 * 1024 * 2);
  float* bQKV  = (float*)carve(1152 * 4);
  float* bOut  = (float*)carve(1024 * 4);
  u16* qkvb    = (u16*)carve((size_t)4096 * QLD * 2);
  u16* vTb     = (u16*)carve((size_t)2 * 64 * SLEN * 2);
  u16* Opart   = (u16*)carve((size_t)2 * 32 * 16 * 128 * 64 * 2);  // 16.8 MB
  float* lpart = (float*)carve((size_t)2 * 32 * 16 * 128 * 4);     // 0.5 MB
  u16* aob     = qkvb;  // qkvb dead after attn_kernel; reuse (8.4 <= 9.4 MB)

  // prep: weight transposes + bias
  prep_w<<<dim3(16, 35), 256, 0, stream>>>(wq, wk, wv, wo, bq, bk, bv, bo,
                                           wT, woT, bQKV, bOut);

  // QKV projection (x converted in staging) + fused V-transpose
  gemm_qkv<<<dim3(9, 64), 256, 0, stream>>>(x, wT, bQKV, qkvb, vTb);

  // flash attention, split-K x2 (R11-bench proven config)
  attn_kernel<<<dim3(16, 32, 2), 256, 0, stream>>>(qkvb, vTb, Opart, lpart);

  // combine parts (single pass over Opart)
  reduce_o<<<dim3(16, 32), 256, 0, stream>>>(Opart, lpart, aob);

  // output projection -> d_out fp32
  gemm_out<<<dim3(8, 64), 256, 0, stream>>>(aob, woT, bOut, (float*)d_out);
}

// Round 16
// 181.883 us; speedup vs baseline: 1.8070x; 1.0559x over previous
//
#include <hip/hip_runtime.h>
#include <stdint.h>

#define SLEN 2048
#define EDIM 1024
#define NH 16
#define HD 64
#define QLD 1152   // qkv packed row: [q 0..1023 | k 1024..1087 | v 1088..1151]

typedef unsigned short u16;
typedef short bf8 __attribute__((ext_vector_type(8)));   // 8 bf16 in 4 VGPRs
typedef float f4 __attribute__((ext_vector_type(4)));
typedef bf8 bf8_a __attribute__((may_alias));
typedef uint2 uint2_a __attribute__((may_alias));
typedef uint4 uint4_a __attribute__((may_alias));

__device__ __forceinline__ float bf2f(u16 u) {
  union { unsigned u; float f; } c; c.u = ((unsigned)u) << 16; return c.f;
}
__device__ __forceinline__ u16 f2bf(float x) {
  union { __bf16 h; u16 u; } c; c.h = (__bf16)x; return c.u;  // HW cvt, RNE
}
__device__ __forceinline__ unsigned pk2bf(float a, float b) {
  union { __bf16 h[2]; unsigned u; } c;
  c.h[0] = (__bf16)a; c.h[1] = (__bf16)b;
  return c.u;
}
__device__ __forceinline__ void async_cp16(u16* lds, const u16* g) {
  __builtin_amdgcn_global_load_lds((__attribute__((address_space(1))) void*)g,
                                   (__attribute__((address_space(3))) void*)lds,
                                   16, 0, 0);
}

// ---------------- fused prep: weight transposes + bias + x-convert -----------
__device__ __forceinline__ void tcvt_tile(const float* src, int srcLd,
                                          u16* dst, int dstLd, int r0, int c0) {
  __shared__ u16 tile[64][65];
  const int t = threadIdx.x;
#pragma unroll
  for (int i = 0; i < 16; ++i) {
    int e = i * 256 + t, rr = e >> 6, cc = e & 63;
    tile[rr][cc] = f2bf(src[(size_t)(r0 + rr) * srcLd + c0 + cc]);
  }
  __syncthreads();
#pragma unroll
  for (int i = 0; i < 16; ++i) {
    int e = i * 256 + t, j = e >> 6, ii = e & 63;
    dst[(size_t)(c0 + j) * dstLd + r0 + ii] = tile[ii][j];
  }
}

__global__ void prep_w(const float* wq, const float* wk, const float* wv,
                       const float* wo, const float* bq, const float* bk,
                       const float* bv, const float* bo, const float* x,
                       u16* wT, u16* woT, float* bQKV, float* bOut, u16* xbf) {
  const int yy = blockIdx.y;
  if (yy < 16) tcvt_tile(wq, 1024, wT, 1024, blockIdx.x * 64, yy * 64);
  else if (yy < 32) tcvt_tile(wo, 1024, woT, 1024, blockIdx.x * 64, (yy - 16) * 64);
  else if (yy == 32) tcvt_tile(wk, 64, wT + (size_t)1024 * 1024, 1024, blockIdx.x * 64, 0);
  else if (yy == 33) tcvt_tile(wv, 64, wT + (size_t)1088 * 1024, 1024, blockIdx.x * 64, 0);
  else if (yy == 34) {
    int i = blockIdx.x * 256 + threadIdx.x;
    if (i < 1024) bQKV[i] = bq[i];
    else if (i < 1088) bQKV[i] = bk[i - 1024];
    else if (i < 1152) bQKV[i] = bv[i - 1088];
    int j = i - 1152;
    if (j >= 0 && j < 1024) bOut[j] = bo[j];
  } else {
    // x fp32 -> bf16: 256 blocks x 256 thr x 64 elems = 4M
    const int blk = (yy - 35) * 16 + blockIdx.x, t = threadIdx.x;
#pragma unroll
    for (int i = 0; i < 8; ++i) {
      int idx = blk * 16384 + i * 2048 + t * 8;
      u16 tmp[8];
#pragma unroll
      for (int j = 0; j < 8; ++j) tmp[j] = f2bf(x[idx + j]);
      *(uint4_a*)&xbf[idx] = *(const uint4_a*)tmp;
    }
  }
}

// ---------------- 64x128 bf16 GEMM, B^T input, async staging -----------------
// XOR chunk swizzle: chunk c of row m at slot m*8 + ((c+m)&7). ofp32: fp32
// epilogue (d_out). vtb: waves covering cols>=1088 also scatter V^T.
__global__ __launch_bounds__(256) void gemm_bt_bias(
    const u16* __restrict__ A, const u16* __restrict__ Bt,
    const float* __restrict__ bias, void* __restrict__ C, int K, int ldc,
    int ofp32, u16* __restrict__ vtb) {
  __shared__ __align__(16) u16 As[64 * 64];
  __shared__ __align__(16) u16 Bs[128 * 64];
  const int tn0 = blockIdx.x * 128, tm0 = blockIdx.y * 64;
  const int tid = threadIdx.x, wave = tid >> 6, lane = tid & 63;
  const int quad = lane >> 4, l16 = lane & 15;
  const int wm = wave & 1, wn = wave >> 1;

  f4 acc[2][4];
#pragma unroll
  for (int i = 0; i < 2; ++i)
#pragma unroll
    for (int j = 0; j < 4; ++j) acc[i][j] = f4{0.f, 0.f, 0.f, 0.f};

  int aslot[2], bslot[4]; size_t aoff[2], boff[4];
#pragma unroll
  for (int i = 0; i < 2; ++i) {
    int s = i * 256 + tid, m = s >> 3, kc = s & 7, c = (kc - m) & 7;
    aslot[i] = s; aoff[i] = (size_t)(tm0 + m) * K + c * 8;
  }
#pragma unroll
  for (int i = 0; i < 4; ++i) {
    int s = i * 256 + tid, n = s >> 3, kc = s & 7, c = (kc - n) & 7;
    bslot[i] = s; boff[i] = (size_t)(tn0 + n) * K + c * 8;
  }
  int ard[2][2], brd[4][2];
#pragma unroll
  for (int mi = 0; mi < 2; ++mi) {
    int m = wm * 32 + mi * 16 + l16;
#pragma unroll
    for (int kk = 0; kk < 2; ++kk)
      ard[mi][kk] = (m * 8 + (((kk * 4 + quad) + m) & 7)) * 8;
  }
#pragma unroll
  for (int ni = 0; ni < 4; ++ni) {
    int n = wn * 64 + ni * 16 + l16;
#pragma unroll
    for (int kk = 0; kk < 2; ++kk)
      brd[ni][kk] = (n * 8 + (((kk * 4 + quad) + n) & 7)) * 8;
  }

  const int kIt = K >> 6;
  for (int it = 0; it < kIt; ++it) {
    __syncthreads();
    const size_t kb = (size_t)it * 64;
#pragma unroll
    for (int i = 0; i < 2; ++i) async_cp16(&As[aslot[i] * 8], A + aoff[i] + kb);
#pragma unroll
    for (int i = 0; i < 4; ++i) async_cp16(&Bs[bslot[i] * 8], Bt + boff[i] + kb);
    __syncthreads();
#pragma unroll
    for (int kk = 0; kk < 2; ++kk) {
      bf8 af[2], bfr[4];
#pragma unroll
      for (int mi = 0; mi < 2; ++mi) af[mi] = *(const bf8_a*)&As[ard[mi][kk]];
#pragma unroll
      for (int ni = 0; ni < 4; ++ni) bfr[ni] = *(const bf8_a*)&Bs[brd[ni][kk]];
#pragma unroll
      for (int mi = 0; mi < 2; ++mi)
#pragma unroll
        for (int ni = 0; ni < 4; ++ni)
          acc[mi][ni] = __builtin_amdgcn_mfma_f32_16x16x32_bf16(
              af[mi], bfr[ni], acc[mi][ni], 0, 0, 0);
    }
  }

  float bv[4];
#pragma unroll
  for (int ni = 0; ni < 4; ++ni) bv[ni] = bias[tn0 + wn * 64 + ni * 16 + l16];
#pragma unroll
  for (int mi = 0; mi < 2; ++mi) {
    int row0 = tm0 + wm * 32 + mi * 16 + quad * 4;
#pragma unroll
    for (int ni = 0; ni < 4; ++ni) {
      int col = tn0 + wn * 64 + ni * 16 + l16;
      float vv[4];
#pragma unroll
      for (int r = 0; r < 4; ++r) vv[r] = acc[mi][ni][r] + bv[ni];
      if (ofp32) {
#pragma unroll
        for (int r = 0; r < 4; ++r)
          ((float*)C)[(size_t)(row0 + r) * ldc + col] = vv[r];
      } else {
#pragma unroll
        for (int r = 0; r < 4; ++r)
          ((u16*)C)[(size_t)(row0 + r) * ldc + col] = f2bf(vv[r]);
      }
      if (vtb != nullptr && col >= 1088) {
        int d = col - 1088, bb = row0 >> 11, s0 = row0 & 2047;
        uint2 pk;
        pk.x = pk2bf(vv[0], vv[1]);
        pk.y = pk2bf(vv[2], vv[3]);
        *(uint2_a*)&vtb[(size_t)(bb * 64 + d) * SLEN + s0] = pk;
      }
    }
  }
}

// ---------------- flash attention (MQA), split-K over key halves -------------
// Grid (16 qt, 32 bh, 2 ks) = 1024 blocks = 4/CU (LDS cap). No-max softmax
// partials are additive: each half writes unnormalized O (bf16) + l (fp32);
// reduce_o combines. 256 thr = 4 waves x 32 q-rows; fragment-major Kf/Vf.
__global__ __launch_bounds__(256, 4) void attn_kernel(
    const u16* __restrict__ qkv, const u16* __restrict__ vT,
    u16* __restrict__ Opart, float* __restrict__ lpart) {
  __shared__ __align__(16) u16 Kf[8192];    // K tile frag-major; Qf in prologue
  __shared__ __align__(16) u16 Vf[8192];
  __shared__ __align__(16) u16 Ps[4096];    // 4 waves x 1024 (one 32-key group)
  const int qt = blockIdx.x, bh = blockIdx.y, ks = blockIdx.z;
  const int b = bh >> 4, h = bh & 15;
  const int tid = threadIdx.x, wave = tid >> 6, lane = tid & 63;
  const int quad = lane >> 4, l16 = lane & 15;

  // Qf stage: chunk d = [kk:1][g:3][qd:2][r16:4]
#pragma unroll
  for (int i = 0; i < 4; ++i) {
    int d = i * 256 + tid;
    int kk = d >> 9, g = (d >> 6) & 7, qd = (d >> 4) & 3, r16 = d & 15;
    async_cp16(&Kf[d * 8],
               qkv + (size_t)(b * SLEN + qt * 128 + g * 16 + r16) * QLD +
                   h * HD + (kk * 4 + qd) * 8);
  }
  __syncthreads();
  bf8 bq[2][2];  // [nt][kk], B-frag rows wave*32 + nt*16 + l16
#pragma unroll
  for (int nt = 0; nt < 2; ++nt)
#pragma unroll
    for (int kk = 0; kk < 2; ++kk)
      bq[nt][kk] = *(const bf8_a*)&Kf[((kk * 8 + wave * 2 + nt) * 64 + lane) * 8];

  f4 acc_o[2][4];
#pragma unroll
  for (int i = 0; i < 2; ++i)
#pragma unroll
    for (int j = 0; j < 4; ++j) acc_o[i][j] = f4{0.f, 0.f, 0.f, 0.f};
  f4 lr4[2] = {f4{0.f, 0.f, 0.f, 0.f}, f4{0.f, 0.f, 0.f, 0.f}};
  const float C1 = 0.125f * 1.44269504089f;  // scale * log2(e)
  const int psb = wave * 1024;

  for (int kt = ks * 8; kt < ks * 8 + 8; ++kt) {
    __syncthreads();  // prior Kf/Vf reads (incl. bq prologue) complete
#pragma unroll
    for (int i = 0; i < 4; ++i) {
      int d = i * 256 + tid;
      int kk = d >> 9, k8 = (d >> 6) & 7, qd = (d >> 4) & 3, r16 = d & 15;
      async_cp16(&Kf[d * 8],
                 qkv + (size_t)(b * SLEN + kt * 128 + k8 * 16 + r16) * QLD +
                     EDIM + (kk * 4 + qd) * 8);
    }
#pragma unroll
    for (int i = 0; i < 4; ++i) {
      int d = i * 256 + tid;
      int k4 = d >> 8, ni = (d >> 6) & 3, qd = (d >> 4) & 3, r16 = d & 15;
      async_cp16(&Vf[d * 8],
                 vT + (size_t)(b * 64 + ni * 16 + r16) * SLEN + kt * 128 +
                     (k4 * 4 + qd) * 8);
    }
    __syncthreads();

    // per-32-key fused groups: QK -> softmax/pack -> wave-private Ps -> PV
#pragma unroll
    for (int k4 = 0; k4 < 4; ++k4) {
      f4 st[2][2];
#pragma unroll
      for (int j = 0; j < 2; ++j)
#pragma unroll
        for (int nt = 0; nt < 2; ++nt) st[j][nt] = f4{0.f, 0.f, 0.f, 0.f};
#pragma unroll
      for (int kk = 0; kk < 2; ++kk)
#pragma unroll
        for (int j = 0; j < 2; ++j) {
          bf8 ak = *(const bf8_a*)&Kf[((kk * 8 + k4 * 2 + j) * 64 + lane) * 8];
#pragma unroll
          for (int nt = 0; nt < 2; ++nt)
            st[j][nt] = __builtin_amdgcn_mfma_f32_16x16x32_bf16(
                ak, bq[nt][kk], st[j][nt], 0, 0, 0);
        }
#pragma unroll
      for (int nt = 0; nt < 2; ++nt)
#pragma unroll
        for (int j = 0; j < 2; ++j) {
          f4 pe;
          pe[0] = __builtin_amdgcn_exp2f(st[j][nt][0] * C1);
          pe[1] = __builtin_amdgcn_exp2f(st[j][nt][1] * C1);
          pe[2] = __builtin_amdgcn_exp2f(st[j][nt][2] * C1);
          pe[3] = __builtin_amdgcn_exp2f(st[j][nt][3] * C1);
          lr4[nt] += pe;
          uint2 pk;
          pk.x = pk2bf(pe[0], pe[1]);
          pk.y = pk2bf(pe[2], pe[3]);
          int qd2 = j * 2 + (quad >> 1);
          *(uint2_a*)&Ps[psb + ((nt * 4 + qd2) * 16 + l16) * 8 + (quad & 1) * 4] = pk;
        }
      asm volatile("" ::: "memory");  // Ps writes before PV reads (same wave)
      bf8 ap[2];
#pragma unroll
      for (int mt = 0; mt < 2; ++mt)
        ap[mt] = *(const bf8_a*)&Ps[psb + ((mt * 4 + quad) * 16 + l16) * 8];
#pragma unroll
      for (int ni = 0; ni < 4; ++ni) {
        bf8 bv = *(const bf8_a*)&Vf[((k4 * 4 + ni) * 64 + lane) * 8];
#pragma unroll
        for (int mt = 0; mt < 2; ++mt)
          acc_o[mt][ni] = __builtin_amdgcn_mfma_f32_16x16x32_bf16(
              ap[mt], bv, acc_o[mt][ni], 0, 0, 0);
      }
      asm volatile("" ::: "memory");  // PV reads before next group's Ps writes
    }
  }

  // store unnormalized partials: O bf16, l fp32
  const size_t pbase = (size_t)((ks * 32 + bh) * 16 + qt) * 128;
  float ls[2];
#pragma unroll
  for (int nt = 0; nt < 2; ++nt) {
    float s = (lr4[nt][0] + lr4[nt][1]) + (lr4[nt][2] + lr4[nt][3]);
    s += __shfl_xor(s, 16, 64);
    s += __shfl_xor(s, 32, 64);
    ls[nt] = s;
    if (quad == 0) lpart[pbase + wave * 32 + nt * 16 + l16] = s;
  }
#pragma unroll
  for (int mt = 0; mt < 2; ++mt)
#pragma unroll
    for (int r = 0; r < 4; ++r) {
      size_t row = pbase + wave * 32 + mt * 16 + quad * 4 + r;
#pragma unroll
      for (int ni = 0; ni < 4; ++ni)
        Opart[row * 64 + ni * 16 + l16] = f2bf(acc_o[mt][ni][r]);
    }
}

// ---------------- combine split-K halves: aob = (O0+O1)/(l0+l1) --------------
__global__ __launch_bounds__(256) void reduce_o(const u16* __restrict__ Op,
                                                const float* __restrict__ lp,
                                                u16* __restrict__ aob) {
  const int qt = blockIdx.x, bh = blockIdx.y, b = bh >> 4, h = bh & 15;
  const int t = threadIdx.x, r = t >> 1, dh = (t & 1) * 32;
  const size_t p0 = (size_t)(bh * 16 + qt) * 128;
  const size_t p1 = (size_t)((32 + bh) * 16 + qt) * 128;
  const float inv = 1.f / (lp[p0 + r] + lp[p1 + r]);
  const u16* o0 = Op + (p0 + r) * 64 + dh;
  const u16* o1 = Op + (p1 + r) * 64 + dh;
  u16* dst = aob + (size_t)(b * SLEN + qt * 128 + r) * EDIM + h * HD + dh;
#pragma unroll
  for (int c = 0; c < 4; ++c) {
    uint4 a = *(const uint4_a*)(o0 + c * 8);
    uint4 bb = *(const uint4_a*)(o1 + c * 8);
    const u16* pa = (const u16*)&a;
    const u16* pb = (const u16*)&bb;
    u16 outv[8];
#pragma unroll
    for (int j = 0; j < 8; ++j)
      outv[j] = f2bf((bf2f(pa[j]) + bf2f(pb[j])) * inv);
    *(uint4_a*)(dst + c * 8) = *(const uint4_a*)outv;
  }
}

// ---------------- host ------------------------------------------------------
extern "C" void kernel_launch(void* const* d_in, const int* in_sizes, int n_in,
                              void* d_out, int out_size, void* d_ws, size_t ws_size,
                              hipStream_t stream) {
  const float* x  = (const float*)d_in[0];
  const float* wq = (const float*)d_in[1];
  const float* bq = (const float*)d_in[2];
  const float* wk = (const float*)d_in[3];
  const float* bk = (const float*)d_in[4];
  const float* wv = (const float*)d_in[5];
  const float* bv = (const float*)d_in[6];
  const float* wo = (const float*)d_in[7];
  const float* bo = (const float*)d_in[8];

  char* ws = (char*)d_ws;
  size_t off = 0;
  auto carve = [&](size_t bytes) {
    void* p = ws + off;
    off = (off + bytes + 255) & ~(size_t)255;
    return p;
  };
  u16* wT      = (u16*)carve((size_t)1152 * 1024 * 2);  // packed [wq|wk|wv]^T
  u16* woT     = (u16*)carve((size_t)1024 * 1024 * 2);
  float* bQKV  = (float*)carve(1152 * 4);
  float* bOut  = (float*)carve(1024 * 4);
  u16* xbf     = (u16*)carve((size_t)4096 * EDIM * 2);
  u16* qkvb    = (u16*)carve((size_t)4096 * QLD * 2);
  u16* vTb     = (u16*)carve((size_t)2 * 64 * SLEN * 2);
  u16* Opart   = (u16*)carve((size_t)2 * 32 * 16 * 128 * 64 * 2);  // 16.8 MB
  float* lpart = (float*)carve((size_t)2 * 32 * 16 * 128 * 4);     // 0.5 MB
  u16* aob     = (u16*)carve((size_t)4096 * EDIM * 2);

  // prep: weight transposes + bias + x-convert (one grid)
  prep_w<<<dim3(16, 51), 256, 0, stream>>>(wq, wk, wv, wo, bq, bk, bv, bo, x,
                                           wT, woT, bQKV, bOut, xbf);

  // QKV projection (+ fused V-transpose): [4096][1024] @ [1024][1152]^T
  gemm_bt_bias<<<dim3(9, 64), 256, 0, stream>>>(xbf, wT, bQKV, qkvb, 1024, QLD,
                                                0, vTb);

  // flash attention, split-K over key halves
  attn_kernel<<<dim3(16, 32, 2), 256, 0, stream>>>(qkvb, vTb, Opart, lpart);
  reduce_o<<<dim3(16, 32), 256, 0, stream>>>(Opart, lpart, aob);

  // output projection + bo -> d_out (fp32)
  gemm_bt_bias<<<dim3(8, 64), 256, 0, stream>>>(aob, woT, bOut, d_out, 1024,
                                                1024, 1, nullptr);
}

// Round 17
// 177.141 us; speedup vs baseline: 1.8554x; 1.0268x over previous
//
#include <hip/hip_runtime.h>
#include <stdint.h>

#define SLEN 2048
#define EDIM 1024
#define NH 16
#define HD 64
#define QLD 1152   // qkv packed row: [q 0..1023 | k 1024..1087 | v 1088..1151]

typedef unsigned short u16;
typedef short bf8 __attribute__((ext_vector_type(8)));   // 8 bf16 in 4 VGPRs
typedef float f4 __attribute__((ext_vector_type(4)));
typedef bf8 bf8_a __attribute__((may_alias));
typedef uint2 uint2_a __attribute__((may_alias));
typedef uint4 uint4_a __attribute__((may_alias));

__device__ __forceinline__ float bf2f(u16 u) {
  union { unsigned u; float f; } c; c.u = ((unsigned)u) << 16; return c.f;
}
__device__ __forceinline__ u16 f2bf(float x) {
  union { __bf16 h; u16 u; } c; c.h = (__bf16)x; return c.u;  // HW cvt, RNE
}
__device__ __forceinline__ unsigned pk2bf(float a, float b) {
  union { __bf16 h[2]; unsigned u; } c;
  c.h[0] = (__bf16)a; c.h[1] = (__bf16)b;
  return c.u;
}
__device__ __forceinline__ void async_cp16(u16* lds, const u16* g) {
  __builtin_amdgcn_global_load_lds((__attribute__((address_space(1))) void*)g,
                                   (__attribute__((address_space(3))) void*)lds,
                                   16, 0, 0);
}

// ---------------- fused prep: weight transposes + bias + x-convert -----------
__device__ __forceinline__ void tcvt_tile(const float* src, int srcLd,
                                          u16* dst, int dstLd, int r0, int c0) {
  __shared__ u16 tile[64][65];
  const int t = threadIdx.x;
#pragma unroll
  for (int i = 0; i < 16; ++i) {
    int e = i * 256 + t, rr = e >> 6, cc = e & 63;
    tile[rr][cc] = f2bf(src[(size_t)(r0 + rr) * srcLd + c0 + cc]);
  }
  __syncthreads();
#pragma unroll
  for (int i = 0; i < 16; ++i) {
    int e = i * 256 + t, j = e >> 6, ii = e & 63;
    dst[(size_t)(c0 + j) * dstLd + r0 + ii] = tile[ii][j];
  }
}

__global__ void prep_w(const float* wq, const float* wk, const float* wv,
                       const float* wo, const float* bq, const float* bk,
                       const float* bv, const float* bo, const float* x,
                       u16* wT, u16* woT, float* bQKV, float* bOut, u16* xbf) {
  const int yy = blockIdx.y;
  if (yy < 16) tcvt_tile(wq, 1024, wT, 1024, blockIdx.x * 64, yy * 64);
  else if (yy < 32) tcvt_tile(wo, 1024, woT, 1024, blockIdx.x * 64, (yy - 16) * 64);
  else if (yy == 32) tcvt_tile(wk, 64, wT + (size_t)1024 * 1024, 1024, blockIdx.x * 64, 0);
  else if (yy == 33) tcvt_tile(wv, 64, wT + (size_t)1088 * 1024, 1024, blockIdx.x * 64, 0);
  else if (yy == 34) {
    int i = blockIdx.x * 256 + threadIdx.x;
    if (i < 1024) bQKV[i] = bq[i];
    else if (i < 1088) bQKV[i] = bk[i - 1024];
    else if (i < 1152) bQKV[i] = bv[i - 1088];
    int j = i - 1152;
    if (j >= 0 && j < 1024) bOut[j] = bo[j];
  } else {
    // x fp32 -> bf16: 256 blocks x 256 thr x 64 elems = 4M
    const int blk = (yy - 35) * 16 + blockIdx.x, t = threadIdx.x;
#pragma unroll
    for (int i = 0; i < 8; ++i) {
      int idx = blk * 16384 + i * 2048 + t * 8;
      u16 tmp[8];
#pragma unroll
      for (int j = 0; j < 8; ++j) tmp[j] = f2bf(x[idx + j]);
      *(uint4_a*)&xbf[idx] = *(const uint4_a*)tmp;
    }
  }
}

// ---------------- 64x128 bf16 GEMM, B^T input, async staging -----------------
// XOR chunk swizzle: chunk c of row m at slot m*8 + ((c+m)&7). ofp32: fp32
// epilogue (d_out). vtb: waves covering cols>=1088 also scatter V^T.
__global__ __launch_bounds__(256) void gemm_bt_bias(
    const u16* __restrict__ A, const u16* __restrict__ Bt,
    const float* __restrict__ bias, void* __restrict__ C, int K, int ldc,
    int ofp32, u16* __restrict__ vtb) {
  __shared__ __align__(16) u16 As[64 * 64];
  __shared__ __align__(16) u16 Bs[128 * 64];
  const int tn0 = blockIdx.x * 128, tm0 = blockIdx.y * 64;
  const int tid = threadIdx.x, wave = tid >> 6, lane = tid & 63;
  const int quad = lane >> 4, l16 = lane & 15;
  const int wm = wave & 1, wn = wave >> 1;

  f4 acc[2][4];
#pragma unroll
  for (int i = 0; i < 2; ++i)
#pragma unroll
    for (int j = 0; j < 4; ++j) acc[i][j] = f4{0.f, 0.f, 0.f, 0.f};

  int aslot[2], bslot[4]; size_t aoff[2], boff[4];
#pragma unroll
  for (int i = 0; i < 2; ++i) {
    int s = i * 256 + tid, m = s >> 3, kc = s & 7, c = (kc - m) & 7;
    aslot[i] = s; aoff[i] = (size_t)(tm0 + m) * K + c * 8;
  }
#pragma unroll
  for (int i = 0; i < 4; ++i) {
    int s = i * 256 + tid, n = s >> 3, kc = s & 7, c = (kc - n) & 7;
    bslot[i] = s; boff[i] = (size_t)(tn0 + n) * K + c * 8;
  }
  int ard[2][2], brd[4][2];
#pragma unroll
  for (int mi = 0; mi < 2; ++mi) {
    int m = wm * 32 + mi * 16 + l16;
#pragma unroll
    for (int kk = 0; kk < 2; ++kk)
      ard[mi][kk] = (m * 8 + (((kk * 4 + quad) + m) & 7)) * 8;
  }
#pragma unroll
  for (int ni = 0; ni < 4; ++ni) {
    int n = wn * 64 + ni * 16 + l16;
#pragma unroll
    for (int kk = 0; kk < 2; ++kk)
      brd[ni][kk] = (n * 8 + (((kk * 4 + quad) + n) & 7)) * 8;
  }

  const int kIt = K >> 6;
  for (int it = 0; it < kIt; ++it) {
    __syncthreads();
    const size_t kb = (size_t)it * 64;
#pragma unroll
    for (int i = 0; i < 2; ++i) async_cp16(&As[aslot[i] * 8], A + aoff[i] + kb);
#pragma unroll
    for (int i = 0; i < 4; ++i) async_cp16(&Bs[bslot[i] * 8], Bt + boff[i] + kb);
    __syncthreads();
#pragma unroll
    for (int kk = 0; kk < 2; ++kk) {
      bf8 af[2], bfr[4];
#pragma unroll
      for (int mi = 0; mi < 2; ++mi) af[mi] = *(const bf8_a*)&As[ard[mi][kk]];
#pragma unroll
      for (int ni = 0; ni < 4; ++ni) bfr[ni] = *(const bf8_a*)&Bs[brd[ni][kk]];
#pragma unroll
      for (int mi = 0; mi < 2; ++mi)
#pragma unroll
        for (int ni = 0; ni < 4; ++ni)
          acc[mi][ni] = __builtin_amdgcn_mfma_f32_16x16x32_bf16(
              af[mi], bfr[ni], acc[mi][ni], 0, 0, 0);
    }
  }

  float bv[4];
#pragma unroll
  for (int ni = 0; ni < 4; ++ni) bv[ni] = bias[tn0 + wn * 64 + ni * 16 + l16];
#pragma unroll
  for (int mi = 0; mi < 2; ++mi) {
    int row0 = tm0 + wm * 32 + mi * 16 + quad * 4;
#pragma unroll
    for (int ni = 0; ni < 4; ++ni) {
      int col = tn0 + wn * 64 + ni * 16 + l16;
      float vv[4];
#pragma unroll
      for (int r = 0; r < 4; ++r) vv[r] = acc[mi][ni][r] + bv[ni];
      if (ofp32) {
#pragma unroll
        for (int r = 0; r < 4; ++r)
          ((float*)C)[(size_t)(row0 + r) * ldc + col] = vv[r];
      } else {
#pragma unroll
        for (int r = 0; r < 4; ++r)
          ((u16*)C)[(size_t)(row0 + r) * ldc + col] = f2bf(vv[r]);
      }
      if (vtb != nullptr && col >= 1088) {
        int d = col - 1088, bb = row0 >> 11, s0 = row0 & 2047;
        uint2 pk;
        pk.x = pk2bf(vv[0], vv[1]);
        pk.y = pk2bf(vv[2], vv[3]);
        *(uint2_a*)&vtb[(size_t)(bb * 64 + d) * SLEN + s0] = pk;
      }
    }
  }
}

// ---------------- flash attention (MQA), split-K, LDS double-buffered --------
// R17: 64-key half-tiles x 2 LDS buffers (same 40KB total -> 4 blocks/CU kept,
// VGPR ~60 kept). Per iter: barrier -> stage(h+1) -> compute(h): the staging
// drain at the next barrier lands after a full compute phase, hiding the
// global-load latency the R16 stage->barrier->compute order exposed.
// Fragment-major Kf/Vf (R16-verified layouts, 64-key range); wave-private Ps.
__global__ __launch_bounds__(256, 4) void attn_kernel(
    const u16* __restrict__ qkv, const u16* __restrict__ vT,
    u16* __restrict__ Opart, float* __restrict__ lpart) {
  __shared__ __align__(16) u16 Kf[2][4096];  // [buf][64 keys x 64 d] frag-major
  __shared__ __align__(16) u16 Vf[2][4096];  // [buf][64 d x 64 keys] frag-major
  __shared__ __align__(16) u16 Ps[4096];     // 4 waves x 1024 (one 32-key group)
  const int qt = blockIdx.x, bh = blockIdx.y, ks = blockIdx.z;
  const int b = bh >> 4, h = bh & 15;
  const int tid = threadIdx.x, wave = tid >> 6, lane = tid & 63;
  const int quad = lane >> 4, l16 = lane & 15;

  // Q prologue into flat Kf (128 rows x 64 = 1024 chunks across both buffers)
  u16* Kflat = &Kf[0][0];
#pragma unroll
  for (int i = 0; i < 4; ++i) {
    int d = i * 256 + tid;
    int kk = d >> 9, g = (d >> 6) & 7, qd = (d >> 4) & 3, r16 = d & 15;
    async_cp16(&Kflat[d * 8],
               qkv + (size_t)(b * SLEN + qt * 128 + g * 16 + r16) * QLD +
                   h * HD + (kk * 4 + qd) * 8);
  }
  __syncthreads();
  bf8 bq[2][2];  // [nt][kk], B-frag rows wave*32 + nt*16 + l16
#pragma unroll
  for (int nt = 0; nt < 2; ++nt)
#pragma unroll
    for (int kk = 0; kk < 2; ++kk)
      bq[nt][kk] = *(const bf8_a*)&Kflat[((kk * 8 + wave * 2 + nt) * 64 + lane) * 8];
  __syncthreads();  // bq reads complete before Kf reused for K tiles

  const int kbase = ks * 1024;  // this split half covers keys kbase..kbase+1023
  auto stage = [&](int hh, int bsel) {
    // Kf half: 512 chunks [kk:1][k8:2][qd:2][r16:4]
#pragma unroll
    for (int i = 0; i < 2; ++i) {
      int d = i * 256 + tid;
      int kk = d >> 8, k8 = (d >> 6) & 3, qd = (d >> 4) & 3, r16 = d & 15;
      async_cp16(&Kf[bsel][d * 8],
                 qkv + (size_t)(b * SLEN + kbase + hh * 64 + k8 * 16 + r16) * QLD +
                     EDIM + (kk * 4 + qd) * 8);
    }
    // Vf half: 512 chunks [k4:1][ni:2][qd:2][r16:4]
#pragma unroll
    for (int i = 0; i < 2; ++i) {
      int d = i * 256 + tid;
      int k4 = d >> 8, ni = (d >> 6) & 3, qd = (d >> 4) & 3, r16 = d & 15;
      async_cp16(&Vf[bsel][d * 8],
                 vT + (size_t)(b * 64 + ni * 16 + r16) * SLEN + kbase + hh * 64 +
                     (k4 * 4 + qd) * 8);
    }
  };
  stage(0, 0);

  f4 acc_o[2][4];
#pragma unroll
  for (int i = 0; i < 2; ++i)
#pragma unroll
    for (int j = 0; j < 4; ++j) acc_o[i][j] = f4{0.f, 0.f, 0.f, 0.f};
  f4 lr4[2] = {f4{0.f, 0.f, 0.f, 0.f}, f4{0.f, 0.f, 0.f, 0.f}};
  const float C1 = 0.125f * 1.44269504089f;  // scale * log2(e)
  const int psb = wave * 1024;

  for (int hh = 0; hh < 16; ++hh) {
    __syncthreads();  // drains staging of half hh; fences buffer reuse
    if (hh < 15) stage(hh + 1, (hh + 1) & 1);
    const int bsel = hh & 1;

    // two 32-key groups per half: QK -> softmax/pack -> wave-private Ps -> PV
#pragma unroll
    for (int k4 = 0; k4 < 2; ++k4) {
      f4 st[2][2];
#pragma unroll
      for (int j = 0; j < 2; ++j)
#pragma unroll
        for (int nt = 0; nt < 2; ++nt) st[j][nt] = f4{0.f, 0.f, 0.f, 0.f};
#pragma unroll
      for (int kk = 0; kk < 2; ++kk)
#pragma unroll
        for (int j = 0; j < 2; ++j) {
          bf8 ak = *(const bf8_a*)&Kf[bsel][((kk * 4 + k4 * 2 + j) * 64 + lane) * 8];
#pragma unroll
          for (int nt = 0; nt < 2; ++nt)
            st[j][nt] = __builtin_amdgcn_mfma_f32_16x16x32_bf16(
                ak, bq[nt][kk], st[j][nt], 0, 0, 0);
        }
#pragma unroll
      for (int nt = 0; nt < 2; ++nt)
#pragma unroll
        for (int j = 0; j < 2; ++j) {
          f4 pe;
          pe[0] = __builtin_amdgcn_exp2f(st[j][nt][0] * C1);
          pe[1] = __builtin_amdgcn_exp2f(st[j][nt][1] * C1);
          pe[2] = __builtin_amdgcn_exp2f(st[j][nt][2] * C1);
          pe[3] = __builtin_amdgcn_exp2f(st[j][nt][3] * C1);
          lr4[nt] += pe;
          uint2 pk;
          pk.x = pk2bf(pe[0], pe[1]);
          pk.y = pk2bf(pe[2], pe[3]);
          int qd2 = j * 2 + (quad >> 1);
          *(uint2_a*)&Ps[psb + ((nt * 4 + qd2) * 16 + l16) * 8 + (quad & 1) * 4] = pk;
        }
      asm volatile("" ::: "memory");  // Ps writes before PV reads (same wave)
      bf8 ap[2];
#pragma unroll
      for (int mt = 0; mt < 2; ++mt)
        ap[mt] = *(const bf8_a*)&Ps[psb + ((mt * 4 + quad) * 16 + l16) * 8];
#pragma unroll
      for (int ni = 0; ni < 4; ++ni) {
        bf8 bv = *(const bf8_a*)&Vf[bsel][((k4 * 4 + ni) * 64 + lane) * 8];
#pragma unroll
        for (int mt = 0; mt < 2; ++mt)
          acc_o[mt][ni] = __builtin_amdgcn_mfma_f32_16x16x32_bf16(
              ap[mt], bv, acc_o[mt][ni], 0, 0, 0);
      }
      asm volatile("" ::: "memory");  // PV reads before next group's Ps writes
    }
  }

  // store unnormalized partials: O bf16, l fp32
  const size_t pbase = (size_t)((ks * 32 + bh) * 16 + qt) * 128;
  float ls[2];
#pragma unroll
  for (int nt = 0; nt < 2; ++nt) {
    float s = (lr4[nt][0] + lr4[nt][1]) + (lr4[nt][2] + lr4[nt][3]);
    s += __shfl_xor(s, 16, 64);
    s += __shfl_xor(s, 32, 64);
    ls[nt] = s;
    if (quad == 0) lpart[pbase + wave * 32 + nt * 16 + l16] = s;
  }
#pragma unroll
  for (int mt = 0; mt < 2; ++mt)
#pragma unroll
    for (int r = 0; r < 4; ++r) {
      size_t row = pbase + wave * 32 + mt * 16 + quad * 4 + r;
#pragma unroll
      for (int ni = 0; ni < 4; ++ni)
        Opart[row * 64 + ni * 16 + l16] = f2bf(acc_o[mt][ni][r]);
    }
}

// ---------------- combine split-K halves: aob = (O0+O1)/(l0+l1) --------------
__global__ __launch_bounds__(256) void reduce_o(const u16* __restrict__ Op,
                                                const float* __restrict__ lp,
                                                u16* __restrict__ aob) {
  const int qt = blockIdx.x, bh = blockIdx.y, b = bh >> 4, h = bh & 15;
  const int t = threadIdx.x, r = t >> 1, dh = (t & 1) * 32;
  const size_t p0 = (size_t)(bh * 16 + qt) * 128;
  const size_t p1 = (size_t)((32 + bh) * 16 + qt) * 128;
  const float inv = 1.f / (lp[p0 + r] + lp[p1 + r]);
  const u16* o0 = Op + (p0 + r) * 64 + dh;
  const u16* o1 = Op + (p1 + r) * 64 + dh;
  u16* dst = aob + (size_t)(b * SLEN + qt * 128 + r) * EDIM + h * HD + dh;
#pragma unroll
  for (int c = 0; c < 4; ++c) {
    uint4 a = *(const uint4_a*)(o0 + c * 8);
    uint4 bb = *(const uint4_a*)(o1 + c * 8);
    const u16* pa = (const u16*)&a;
    const u16* pb = (const u16*)&bb;
    u16 outv[8];
#pragma unroll
    for (int j = 0; j < 8; ++j)
      outv[j] = f2bf((bf2f(pa[j]) + bf2f(pb[j])) * inv);
    *(uint4_a*)(dst + c * 8) = *(const uint4_a*)outv;
  }
}

// ---------------- host ------------------------------------------------------
extern "C" void kernel_launch(void* const* d_in, const int* in_sizes, int n_in,
                              void* d_out, int out_size, void* d_ws, size_t ws_size,
                              hipStream_t stream) {
  const float* x  = (const float*)d_in[0];
  const float* wq = (const float*)d_in[1];
  const float* bq = (const float*)d_in[2];
  const float* wk = (const float*)d_in[3];
  const float* bk = (const float*)d_in[4];
  const float* wv = (const float*)d_in[5];
  const float* bv = (const float*)d_in[6];
  const float* wo = (const float*)d_in[7];
  const float* bo = (const float*)d_in[8];

  char* ws = (char*)d_ws;
  size_t off = 0;
  auto carve = [&](size_t bytes) {
    void* p = ws + off;
    off = (off + bytes + 255) & ~(size_t)255;
    return p;
  };
  u16* wT      = (u16*)carve((size_t)1152 * 1024 * 2);  // packed [wq|wk|wv]^T
  u16* woT     = (u16*)carve((size_t)1024 * 1024 * 2);
  float* bQKV  = (float*)carve(1152 * 4);
  float* bOut  = (float*)carve(1024 * 4);
  u16* xbf     = (u16*)carve((size_t)4096 * EDIM * 2);
  u16* qkvb    = (u16*)carve((size_t)4096 * QLD * 2);
  u16* vTb     = (u16*)carve((size_t)2 * 64 * SLEN * 2);
  u16* Opart   = (u16*)carve((size_t)2 * 32 * 16 * 128 * 64 * 2);  // 16.8 MB
  float* lpart = (float*)carve((size_t)2 * 32 * 16 * 128 * 4);     // 0.5 MB
  u16* aob     = (u16*)carve((size_t)4096 * EDIM * 2);

  // prep: weight transposes + bias + x-convert (one grid)
  prep_w<<<dim3(16, 51), 256, 0, stream>>>(wq, wk, wv, wo, bq, bk, bv, bo, x,
                                           wT, woT, bQKV, bOut, xbf);

  // QKV projection (+ fused V-transpose): [4096][1024] @ [1024][1152]^T
  gemm_bt_bias<<<dim3(9, 64), 256, 0, stream>>>(xbf, wT, bQKV, qkvb, 1024, QLD,
                                                0, vTb);

  // flash attention, split-K over key halves (double-buffered 64-key tiles)
  attn_kernel<<<dim3(16, 32, 2), 256, 0, stream>>>(qkvb, vTb, Opart, lpart);
  reduce_o<<<dim3(16, 32), 256, 0, stream>>>(Opart, lpart, aob);

  // output projection + bo -> d_out (fp32)
  gemm_bt_bias<<<dim3(8, 64), 256, 0, stream>>>(aob, woT, bOut, d_out, 1024,
                                                1024, 1, nullptr);
}